// Round 1
// baseline (234.366 us; speedup 1.0000x reference)
//
#include <hip/hip_runtime.h>
#include <cstdint>
#include <cstddef>

// Problem constants (fixed by reference)
constexpr int B_ = 8, N_ = 4096, C_ = 256, H_ = 4, D_ = 64, P_ = 64;
constexpr int OC_ = 4 * C_;      // 1024 qkvv channels
constexpr int M_  = B_ * N_;     // 32768 tokens
constexpr int GX_ROWS = 320;     // 256 G rows + 64 xEt rows (per batch)
constexpr int KSPLIT_G = 8;      // token splits for gram atomics

#define DEV_INLINE __device__ __forceinline__

typedef unsigned short ushort_t;
typedef __attribute__((ext_vector_type(8))) short short8;    // 8 bf16 = 4 VGPR
typedef __attribute__((ext_vector_type(4))) short short4v;   // 4 bf16 = 8 B
typedef __attribute__((ext_vector_type(4))) float floatx4;   // MFMA acc

DEV_INLINE short f2bf(float f) {  // RNE f32 -> bf16
  unsigned int u = __builtin_bit_cast(unsigned int, f);
  u += 0x7FFFu + ((u >> 16) & 1u);
  return (short)(u >> 16);
}
DEV_INLINE float bf2f(ushort_t u) {
  return __builtin_bit_cast(float, (unsigned int)u << 16);
}

// ---------------------------------------------------------------------------
// One-shot f32 -> bf16 cast of x, W_qkvv, W_out1, W_out2, W_E (memory-bound).
constexpr size_t X4_  = (size_t)M_ * C_ / 4;       // 2,097,152 float4
constexpr size_t WQ4_ = (size_t)OC_ * C_ / 4;      //    65,536
constexpr size_t W14_ = (size_t)128 * C_ / 4;      //     8,192
constexpr size_t WE4_ = (size_t)P_ * N_ / 4;       //    65,536
constexpr size_t TOT4_ = X4_ + WQ4_ + 2 * W14_ + WE4_;

__global__ __launch_bounds__(256) void k_cast(const float* __restrict__ x,
                                              const float* __restrict__ Wq,
                                              const float* __restrict__ W1,
                                              const float* __restrict__ W2,
                                              const float* __restrict__ WE,
                                              ushort_t* __restrict__ xb,
                                              ushort_t* __restrict__ wqb,
                                              ushort_t* __restrict__ w1b,
                                              ushort_t* __restrict__ w2b,
                                              ushort_t* __restrict__ web) {
  const size_t stride = (size_t)gridDim.x * 256;
  for (size_t i = blockIdx.x * 256 + threadIdx.x; i < TOT4_; i += stride) {
    const float* src;
    ushort_t* dst;
    size_t o;
    if (i < X4_) { src = x; dst = xb; o = i; }
    else if (i < X4_ + WQ4_) { src = Wq; dst = wqb; o = i - X4_; }
    else if (i < X4_ + WQ4_ + W14_) { src = W1; dst = w1b; o = i - X4_ - WQ4_; }
    else if (i < X4_ + WQ4_ + 2 * W14_) { src = W2; dst = w2b; o = i - X4_ - WQ4_ - W14_; }
    else { src = WE; dst = web; o = i - X4_ - WQ4_ - 2 * W14_; }
    float4 v = ((const float4*)src)[o];
    short4v s = {f2bf(v.x), f2bf(v.y), f2bf(v.z), f2bf(v.w)};
    *(short4v*)&dst[o * 4] = s;
  }
}

// ---------------------------------------------------------------------------
// Gram stage: Gx[b] = [ x_b^T x_b  (rows 0..255) ;  WE @ x_b  (rows 256..319) ]
// f32, accumulated with atomicAdd over KSPLIT_G token splits.
// blockIdx.x = job 0..5: ablk = job>>1 in {0,1: x^T 128-ch blk, 2: WE}, bblk = job&1.
// blockIdx.y = b*8 + ksp.
__global__ __launch_bounds__(256) void k_gram(const ushort_t* __restrict__ xb,
                                              const ushort_t* __restrict__ web,
                                              float* __restrict__ Gx) {
  __shared__ __align__(16) short As[128 * 64];
  __shared__ __align__(16) short Bs[128 * 64];
  const int job = blockIdx.x;
  const int ablk = job >> 1;
  const int bblk = job & 1;
  const int b = blockIdx.y >> 3;
  const int ksp = blockIdx.y & 7;
  const int t = threadIdx.x;
  const int lane = t & 63, wave = t >> 6;
  const int m16 = lane & 15, quad = lane >> 4;
  const int wm = (wave >> 1) << 6, wn = (wave & 1) << 6;
  floatx4 acc[4][4];
#pragma unroll
  for (int i = 0; i < 4; ++i)
#pragma unroll
    for (int j = 0; j < 4; ++j) acc[i][j] = (floatx4)(0.f);
  if (ablk == 2) {  // zero As rows 64..127 (discarded pad region; keeps MFMA finite)
#pragma unroll
    for (int i = 0; i < 8; ++i)
      *(unsigned int*)&As[64 * 64 + (i * 256 + t) * 2] = 0u;
  }
  const int c0 = (t & 31) * 4;   // channel quad for transposed staging
  const int tp = t >> 5;         // 0..7 token-pair group
#pragma unroll 1
  for (int it = 0; it < N_ / KSPLIT_G / 64; ++it) {  // 8 iters x 64 tokens
    const int n0 = ksp * (N_ / KSPLIT_G) + it * 64;
    __syncthreads();
    // stage B: x^T tile, channels bblk*128 + c, tokens n0..n0+63 (transposed + XOR swz)
#pragma unroll
    for (int q = 0; q < 4; ++q) {
      const int tok = q * 16 + 2 * tp;
      const size_t r0 = (size_t)(b * N_ + n0 + tok) * C_ + bblk * 128 + c0;
      short4v aa = *(const short4v*)&xb[r0];
      short4v cc = *(const short4v*)&xb[r0 + C_];
#pragma unroll
      for (int i = 0; i < 4; ++i) {
        const int r = c0 + i;
        const int col = tok ^ (8 * ((r >> 3) & 7));
        unsigned int w = (unsigned int)(ushort_t)aa[i] |
                         ((unsigned int)(ushort_t)cc[i] << 16);
        *(unsigned int*)&Bs[r * 64 + col] = w;
      }
    }
    // stage A: x^T tile or WE rows (natural layout)
    if (ablk < 2) {
#pragma unroll
      for (int q = 0; q < 4; ++q) {
        const int tok = q * 16 + 2 * tp;
        const size_t r0 = (size_t)(b * N_ + n0 + tok) * C_ + ablk * 128 + c0;
        short4v aa = *(const short4v*)&xb[r0];
        short4v cc = *(const short4v*)&xb[r0 + C_];
#pragma unroll
        for (int i = 0; i < 4; ++i) {
          const int r = c0 + i;
          const int col = tok ^ (8 * ((r >> 3) & 7));
          unsigned int w = (unsigned int)(ushort_t)aa[i] |
                           ((unsigned int)(ushort_t)cc[i] << 16);
          *(unsigned int*)&As[r * 64 + col] = w;
        }
      }
    } else {
      const int oc8 = (t & 7) * 8;
      const int p0 = t >> 3;   // 0..31
#pragma unroll
      for (int q = 0; q < 2; ++q) {
        const int p = p0 + 32 * q;
        short8 v = *(const short8*)&web[(size_t)p * N_ + n0 + oc8];
        *(short8*)&As[p * 64 + (oc8 ^ (8 * ((p >> 3) & 7)))] = v;
      }
    }
    __syncthreads();
#pragma unroll
    for (int ks = 0; ks < 2; ++ks) {
      const int boct = ks * 32 + quad * 8;
      short8 af[4], bf[4];
#pragma unroll
      for (int i = 0; i < 4; ++i) {
        const int rA = wm + i * 16 + m16;
        af[i] = *(const short8*)&As[rA * 64 + (boct ^ (8 * ((rA >> 3) & 7)))];
      }
#pragma unroll
      for (int j = 0; j < 4; ++j) {
        const int rB = wn + j * 16 + m16;
        bf[j] = *(const short8*)&Bs[rB * 64 + (boct ^ (8 * ((rB >> 3) & 7)))];
      }
#pragma unroll
      for (int i = 0; i < 4; ++i)
#pragma unroll
        for (int j = 0; j < 4; ++j)
          acc[i][j] = __builtin_amdgcn_mfma_f32_16x16x32_bf16(af[i], bf[j], acc[i][j], 0, 0, 0);
    }
  }
#pragma unroll
  for (int i = 0; i < 4; ++i)
#pragma unroll
    for (int r = 0; r < 4; ++r) {
      const int rib = wm + i * 16 + quad * 4 + r;
      if (ablk == 2 && rib >= 64) continue;   // WE job: only 64 valid rows
      const size_t rowoff =
          ((size_t)b * GX_ROWS + ablk * 128 + rib) * 256 + bblk * 128 + wn;
#pragma unroll
      for (int j = 0; j < 4; ++j)
        atomicAdd(&Gx[rowoff + 16 * j + m16], acc[i][j][r]);
    }
}

__global__ __launch_bounds__(256) void k_gcast(const float* __restrict__ Gx,
                                               ushort_t* __restrict__ Gxb) {
  const int i = blockIdx.x * 256 + threadIdx.x;  // 640 blocks -> 655360/4 exact
  float4 v = ((const float4*)Gx)[i];
  short4v s = {f2bf(v.x), f2bf(v.y), f2bf(v.z), f2bf(v.w)};
  *(short4v*)&Gxb[i * 4] = s;
}

// ---------------------------------------------------------------------------
// qv = xb @ W_sel^T: only q (W rows 0..255) and v_ca (W rows 512..767).
// Output bf16 [32768][512]: cols 0..255 = q, 256..511 = v_ca.
__global__ __launch_bounds__(256) void k_qv_mfma(const ushort_t* __restrict__ xb,
                                                 const ushort_t* __restrict__ wqb,
                                                 ushort_t* __restrict__ qv) {
  __shared__ __align__(16) short As[128 * 72];
  __shared__ __align__(16) short Bs[128 * 72];
  const int bm = blockIdx.x * 128;
  const int bo = blockIdx.y * 128;                 // output col base 0..384
  const int wrow_base = bo < 256 ? bo : bo + 256;  // skip k rows (256..511)
  const int t = threadIdx.x;
  const int oc = t & 7;
  const int rr = t >> 3;
  const int lane = t & 63, wave = t >> 6;
  const int m16 = lane & 15, quad = lane >> 4;
  const int wm = (wave >> 1) << 6, wn = (wave & 1) << 6;
  floatx4 acc[4][4];
#pragma unroll
  for (int i = 0; i < 4; ++i)
#pragma unroll
    for (int j = 0; j < 4; ++j) acc[i][j] = (floatx4)(0.f);
#pragma unroll 1
  for (int k0 = 0; k0 < 256; k0 += 64) {
    short8 a8[4], b8[4];
#pragma unroll
    for (int j = 0; j < 4; ++j) {
      const int r = rr + 32 * j;
      a8[j] = *(const short8*)&xb[(size_t)(bm + r) * 256 + k0 + 8 * oc];
      b8[j] = *(const short8*)&wqb[(size_t)(wrow_base + r) * 256 + k0 + 8 * oc];
    }
    __syncthreads();
#pragma unroll
    for (int j = 0; j < 4; ++j) {
      const int r = rr + 32 * j;
      *(short8*)&As[r * 72 + 8 * oc] = a8[j];
      *(short8*)&Bs[r * 72 + 8 * oc] = b8[j];
    }
    __syncthreads();
#pragma unroll
    for (int ks = 0; ks < 2; ++ks) {
      short8 af[4], bf[4];
#pragma unroll
      for (int i = 0; i < 4; ++i)
        af[i] = *(const short8*)&As[(wm + i * 16 + m16) * 72 + ks * 32 + quad * 8];
#pragma unroll
      for (int j = 0; j < 4; ++j)
        bf[j] = *(const short8*)&Bs[(wn + j * 16 + m16) * 72 + ks * 32 + quad * 8];
#pragma unroll
      for (int i = 0; i < 4; ++i)
#pragma unroll
        for (int j = 0; j < 4; ++j)
          acc[i][j] = __builtin_amdgcn_mfma_f32_16x16x32_bf16(af[i], bf[j], acc[i][j], 0, 0, 0);
    }
  }
#pragma unroll
  for (int i = 0; i < 4; ++i)
#pragma unroll
    for (int r = 0; r < 4; ++r) {
      const int gr = bm + wm + i * 16 + quad * 4 + r;
#pragma unroll
      for (int j = 0; j < 4; ++j)
        qv[(size_t)gr * 512 + bo + wn + j * 16 + m16] = (ushort_t)f2bf(acc[i][j][r]);
    }
}

// ---------------------------------------------------------------------------
// T2 = W[0:512] @ G_b (G symmetric): out[i][c] = sum_c' W[i,c'] G[c',c]. bf16 out.
__global__ __launch_bounds__(256) void k_t2gemm(const ushort_t* __restrict__ wqb,
                                                const ushort_t* __restrict__ Gxb,
                                                ushort_t* __restrict__ T2b) {
  __shared__ __align__(16) short As[128 * 72];
  __shared__ __align__(16) short Bs[128 * 72];
  const int bm = blockIdx.x * 128;     // W rows 0..511
  const int b  = blockIdx.y >> 1;
  const int jb = blockIdx.y & 1;       // G col block
  const int t = threadIdx.x;
  const int oc = t & 7;
  const int rr = t >> 3;
  const int lane = t & 63, wave = t >> 6;
  const int m16 = lane & 15, quad = lane >> 4;
  const int wm = (wave >> 1) << 6, wn = (wave & 1) << 6;
  const ushort_t* Bsrc = Gxb + ((size_t)b * GX_ROWS + jb * 128) * 256;
  floatx4 acc[4][4];
#pragma unroll
  for (int i = 0; i < 4; ++i)
#pragma unroll
    for (int j = 0; j < 4; ++j) acc[i][j] = (floatx4)(0.f);
#pragma unroll 1
  for (int k0 = 0; k0 < 256; k0 += 64) {
    short8 a8[4], b8[4];
#pragma unroll
    for (int j = 0; j < 4; ++j) {
      const int r = rr + 32 * j;
      a8[j] = *(const short8*)&wqb[(size_t)(bm + r) * 256 + k0 + 8 * oc];
      b8[j] = *(const short8*)&Bsrc[(size_t)r * 256 + k0 + 8 * oc];
    }
    __syncthreads();
#pragma unroll
    for (int j = 0; j < 4; ++j) {
      const int r = rr + 32 * j;
      *(short8*)&As[r * 72 + 8 * oc] = a8[j];
      *(short8*)&Bs[r * 72 + 8 * oc] = b8[j];
    }
    __syncthreads();
#pragma unroll
    for (int ks = 0; ks < 2; ++ks) {
      short8 af[4], bf[4];
#pragma unroll
      for (int i = 0; i < 4; ++i)
        af[i] = *(const short8*)&As[(wm + i * 16 + m16) * 72 + ks * 32 + quad * 8];
#pragma unroll
      for (int j = 0; j < 4; ++j)
        bf[j] = *(const short8*)&Bs[(wn + j * 16 + m16) * 72 + ks * 32 + quad * 8];
#pragma unroll
      for (int i = 0; i < 4; ++i)
#pragma unroll
        for (int j = 0; j < 4; ++j)
          acc[i][j] = __builtin_amdgcn_mfma_f32_16x16x32_bf16(af[i], bf[j], acc[i][j], 0, 0, 0);
    }
  }
#pragma unroll
  for (int i = 0; i < 4; ++i)
#pragma unroll
    for (int r = 0; r < 4; ++r) {
      const int gr = bm + wm + i * 16 + quad * 4 + r;  // 0..511
#pragma unroll
      for (int j = 0; j < 4; ++j)
        T2b[((size_t)b * 512 + gr) * 256 + jb * 128 + wn + j * 16 + m16] =
            (ushort_t)f2bf(acc[i][j][r]);
    }
}

// rn[b*512+row] = 1/max(sqrt(sum_c W[row,c]*T2[b,row,c]), 1e-12)  (= diag quad form)
__global__ __launch_bounds__(256) void k_rn(const ushort_t* __restrict__ wqb,
                                            const ushort_t* __restrict__ T2b,
                                            float* __restrict__ rn) {
  const int row_g = blockIdx.x * 4 + (threadIdx.x >> 6);  // 0..4095
  const int lane = threadIdx.x & 63;
  const int b = row_g >> 9, row = row_g & 511;
  const short4v w  = *(const short4v*)&wqb[(size_t)row * 256 + lane * 4];
  const short4v tv = *(const short4v*)&T2b[((size_t)b * 512 + row) * 256 + lane * 4];
  float s = 0.f;
#pragma unroll
  for (int i = 0; i < 4; ++i) s += bf2f((ushort_t)w[i]) * bf2f((ushort_t)tv[i]);
#pragma unroll
  for (int o = 32; o; o >>= 1) s += __shfl_xor(s, o);
  if (lane == 0) rn[row_g] = 1.f / fmaxf(sqrtf(s), 1e-12f);
}

// ---------------------------------------------------------------------------
// Per-(b,h) small GEMMs from Gram factors. One wave per 64x64 job, K=256.
// job 0: Sqk[d][e] = Wq_h[d,:] . T2k[e,:]      -> f32 Sqk
// job 1: kp[d][p]  = Wk_h[d,:] . xEt[p,:]      -> ksb[p][d] = bf16((kp+bE)*rn_q*t2)
// job 2: vp[d][p]  = Wv2_h[d,:] . xEt[p,:]     -> vsb[d][p] = bf16(vp+bE)
__global__ __launch_bounds__(64) void k_small(const ushort_t* __restrict__ wqb,
                                              const ushort_t* __restrict__ T2b,
                                              const ushort_t* __restrict__ Gxb,
                                              const float* __restrict__ bE,
                                              const float* __restrict__ rn,
                                              const float* __restrict__ t2,
                                              float* __restrict__ Sqk,
                                              ushort_t* __restrict__ ksb,
                                              ushort_t* __restrict__ vsb) {
  const int bh = blockIdx.x;
  const int job = blockIdx.y;
  const int b = bh >> 2, h = bh & 3;
  const int lane = threadIdx.x & 63;
  const int m16 = lane & 15, quad = lane >> 4;
  const int Abase = (job == 0 ? 0 : (job == 1 ? 256 : 768)) + h * 64;
  const ushort_t* Bp = (job == 0)
      ? T2b + ((size_t)b * 512 + 256 + h * 64) * 256
      : Gxb + ((size_t)b * GX_ROWS + 256) * 256;   // xEt rows [p][c]
  floatx4 acc[4][4];
#pragma unroll
  for (int i = 0; i < 4; ++i)
#pragma unroll
    for (int j = 0; j < 4; ++j) acc[i][j] = (floatx4)(0.f);
#pragma unroll
  for (int ks = 0; ks < 8; ++ks) {
    const int boct = ks * 32 + quad * 8;
    short8 af[4], bf[4];
#pragma unroll
    for (int i = 0; i < 4; ++i)
      af[i] = *(const short8*)&wqb[(size_t)(Abase + 16 * i + m16) * 256 + boct];
#pragma unroll
    for (int j = 0; j < 4; ++j)
      bf[j] = *(const short8*)&Bp[(size_t)(16 * j + m16) * 256 + boct];
#pragma unroll
    for (int i = 0; i < 4; ++i)
#pragma unroll
      for (int j = 0; j < 4; ++j)
        acc[i][j] = __builtin_amdgcn_mfma_f32_16x16x32_bf16(af[i], bf[j], acc[i][j], 0, 0, 0);
  }
  if (job == 0) {
#pragma unroll
    for (int i = 0; i < 4; ++i)
#pragma unroll
      for (int r = 0; r < 4; ++r) {
        const int d = 16 * i + quad * 4 + r;
#pragma unroll
        for (int j = 0; j < 4; ++j)
          Sqk[(size_t)bh * 4096 + d * 64 + 16 * j + m16] = acc[i][j][r];
      }
  } else if (job == 1) {
    const float tt = t2[h];
#pragma unroll
    for (int i = 0; i < 4; ++i)
#pragma unroll
      for (int r = 0; r < 4; ++r) {
        const int d = 16 * i + quad * 4 + r;
        const float rq = rn[b * 512 + h * 64 + d];
#pragma unroll
        for (int j = 0; j < 4; ++j) {
          const int p = 16 * j + m16;
          ksb[(size_t)bh * 4096 + p * 64 + d] =
              (ushort_t)f2bf((acc[i][j][r] + bE[p]) * rq * tt);
        }
      }
  } else {
#pragma unroll
    for (int i = 0; i < 4; ++i)
#pragma unroll
      for (int r = 0; r < 4; ++r) {
        const int d = 16 * i + quad * 4 + r;
#pragma unroll
        for (int j = 0; j < 4; ++j) {
          const int p = 16 * j + m16;
          vsb[(size_t)bh * 4096 + d * 64 + p] = (ushort_t)f2bf(acc[i][j][r] + bE[p]);
        }
      }
  }
}

// ---------------------------------------------------------------------------
// Channel-attn softmax -> bf16 attn [bh][d][e].
__global__ __launch_bounds__(256) void k_ca_softmax(const float* __restrict__ Sqk,
                                                    const float* __restrict__ rn,
                                                    const float* __restrict__ temp,
                                                    ushort_t* __restrict__ ab) {
  const int w = threadIdx.x >> 6;
  const int lane = threadIdx.x & 63;
  const int row = blockIdx.x * 4 + w;  // 0..2047 == b*256 + h*64 + dd
  const int b = row >> 8;
  const int rem = row & 255;
  const int h = rem >> 6;
  const float rq = rn[b * 512 + rem];
  const float rk = rn[b * 512 + 256 + h * 64 + lane];
  float l = Sqk[(size_t)row * 64 + lane] * rq * rk * temp[h];
  float m = l;
#pragma unroll
  for (int o = 32; o; o >>= 1) m = fmaxf(m, __shfl_xor(m, o));
  const float e = __expf(l - m);
  float s = e;
#pragma unroll
  for (int o = 32; o; o >>= 1) s += __shfl_xor(s, o);
  ab[(size_t)row * 64 + lane] = (ushort_t)f2bf(e / s);
}

// ---------------------------------------------------------------------------
// x_ca = attn @ v_ca per (b,h): MFMA, all fragments direct global 16B loads.
__global__ __launch_bounds__(256) void k_ca_mfma(const ushort_t* __restrict__ qv,
                                                 const ushort_t* __restrict__ ab,
                                                 ushort_t* __restrict__ x_ca) {
  const int bh = blockIdx.x;
  const int b = bh >> 2, h = bh & 3;
  const int n0 = blockIdx.y * 128;
  const int lane = threadIdx.x & 63, wave = threadIdx.x >> 6;
  const int m16 = lane & 15, quad = lane >> 4;
  const ushort_t* abb = ab + (size_t)bh * 4096;
  short8 bf[2][4];
#pragma unroll
  for (int ks = 0; ks < 2; ++ks)
#pragma unroll
    for (int j = 0; j < 4; ++j)
      bf[ks][j] = *(const short8*)&abb[(16 * j + m16) * 64 + ks * 32 + quad * 8];
#pragma unroll
  for (int mm = 0; mm < 2; ++mm) {
    const int tokbase = n0 + 64 * mm + 16 * wave;
    const ushort_t* vrow =
        qv + (size_t)(b * N_ + tokbase + m16) * 512 + 256 + h * 64 + quad * 8;
    short8 af0 = *(const short8*)&vrow[0];
    short8 af1 = *(const short8*)&vrow[32];
    floatx4 o[4];
#pragma unroll
    for (int j = 0; j < 4; ++j) o[j] = (floatx4)(0.f);
#pragma unroll
    for (int j = 0; j < 4; ++j) {
      o[j] = __builtin_amdgcn_mfma_f32_16x16x32_bf16(af0, bf[0][j], o[j], 0, 0, 0);
      o[j] = __builtin_amdgcn_mfma_f32_16x16x32_bf16(af1, bf[1][j], o[j], 0, 0, 0);
    }
#pragma unroll
    for (int j = 0; j < 4; ++j)
#pragma unroll
      for (int r = 0; r < 4; ++r)
        x_ca[(size_t)(b * N_ + tokbase + quad * 4 + r) * C_ + h * 64 + 16 * j + m16] =
            (ushort_t)f2bf(o[j][r]);
  }
}

// ---------------------------------------------------------------------------
// Spatial attention, full-MFMA. Per wave: 16 tokens.
__global__ __launch_bounds__(256) void k_sa_mfma(const ushort_t* __restrict__ qv,
                                                 const ushort_t* __restrict__ ksb,
                                                 const ushort_t* __restrict__ vsb,
                                                 ushort_t* __restrict__ x_sa) {
  __shared__ float Pl[64][68];
  const int bh = blockIdx.x;
  const int b = bh >> 2, h = bh & 3;
  const int n0 = blockIdx.y * 64;
  const int lane = threadIdx.x & 63, wave = threadIdx.x >> 6;
  const int m16 = lane & 15, quad = lane >> 4;
  const ushort_t* qrow =
      qv + (size_t)(b * N_ + n0 + 16 * wave + m16) * 512 + h * 64 + quad * 8;
  short8 qf0 = *(const short8*)&qrow[0];
  short8 qf1 = *(const short8*)&qrow[32];
  const ushort_t* kb = ksb + (size_t)bh * 4096;
  const ushort_t* vb = vsb + (size_t)bh * 4096;
  short8 kf[2][4], vf[2][4];
#pragma unroll
  for (int ks = 0; ks < 2; ++ks)
#pragma unroll
    for (int j = 0; j < 4; ++j) {
      kf[ks][j] = *(const short8*)&kb[(16 * j + m16) * 64 + ks * 32 + quad * 8];
      vf[ks][j] = *(const short8*)&vb[(16 * j + m16) * 64 + ks * 32 + quad * 8];
    }
  floatx4 s[4];
#pragma unroll
  for (int j = 0; j < 4; ++j) s[j] = (floatx4)(0.f);
#pragma unroll
  for (int j = 0; j < 4; ++j) {
    s[j] = __builtin_amdgcn_mfma_f32_16x16x32_bf16(qf0, kf[0][j], s[j], 0, 0, 0);
    s[j] = __builtin_amdgcn_mfma_f32_16x16x32_bf16(qf1, kf[1][j], s[j], 0, 0, 0);
  }
  float p[4][4];
#pragma unroll
  for (int r = 0; r < 4; ++r) {
    float mr = fmaxf(fmaxf(s[0][r], s[1][r]), fmaxf(s[2][r], s[3][r]));
    mr = fmaxf(mr, __shfl_xor(mr, 1));
    mr = fmaxf(mr, __shfl_xor(mr, 2));
    mr = fmaxf(mr, __shfl_xor(mr, 4));
    mr = fmaxf(mr, __shfl_xor(mr, 8));
    float sr = 0.f;
#pragma unroll
    for (int j = 0; j < 4; ++j) {
      const float e = __expf(s[j][r] - mr);
      p[j][r] = e;
      sr += e;
    }
    sr += __shfl_xor(sr, 1);
    sr += __shfl_xor(sr, 2);
    sr += __shfl_xor(sr, 4);
    sr += __shfl_xor(sr, 8);
    const float inv = 1.f / sr;
#pragma unroll
    for (int j = 0; j < 4; ++j) p[j][r] *= inv;
  }
#pragma unroll
  for (int j = 0; j < 4; ++j)
#pragma unroll
    for (int r = 0; r < 4; ++r)
      Pl[16 * wave + quad * 4 + r][16 * j + m16] = p[j][r];
  __syncthreads();
  short8 pf[2];
#pragma unroll
  for (int ks = 0; ks < 2; ++ks) {
    float4 x0 = *(const float4*)&Pl[16 * wave + m16][ks * 32 + quad * 8];
    float4 x1 = *(const float4*)&Pl[16 * wave + m16][ks * 32 + quad * 8 + 4];
    short8 v;
    v[0] = f2bf(x0.x); v[1] = f2bf(x0.y); v[2] = f2bf(x0.z); v[3] = f2bf(x0.w);
    v[4] = f2bf(x1.x); v[5] = f2bf(x1.y); v[6] = f2bf(x1.z); v[7] = f2bf(x1.w);
    pf[ks] = v;
  }
  floatx4 o[4];
#pragma unroll
  for (int j = 0; j < 4; ++j) o[j] = (floatx4)(0.f);
#pragma unroll
  for (int j = 0; j < 4; ++j) {
    o[j] = __builtin_amdgcn_mfma_f32_16x16x32_bf16(pf[0], vf[0][j], o[j], 0, 0, 0);
    o[j] = __builtin_amdgcn_mfma_f32_16x16x32_bf16(pf[1], vf[1][j], o[j], 0, 0, 0);
  }
#pragma unroll
  for (int j = 0; j < 4; ++j)
#pragma unroll
    for (int r = 0; r < 4; ++r)
      x_sa[(size_t)(b * N_ + n0 + 16 * wave + quad * 4 + r) * C_ + h * 64 + 16 * j + m16] =
          (ushort_t)f2bf(o[j][r]);
}

// ---------------------------------------------------------------------------
// out[:, half*128 + 0:128] = PReLU(A @ W^T + bias); A, W bf16.
__global__ __launch_bounds__(256) void k_out_mfma(const ushort_t* __restrict__ xsa,
                                                  const ushort_t* __restrict__ xca,
                                                  const ushort_t* __restrict__ w1b,
                                                  const float* __restrict__ b1,
                                                  const ushort_t* __restrict__ w2b,
                                                  const float* __restrict__ b2,
                                                  const float* __restrict__ pa,
                                                  float* __restrict__ out) {
  __shared__ __align__(16) short As[128 * 72];
  __shared__ __align__(16) short Bs[128 * 72];
  const int bm = blockIdx.x * 128;
  const int half = blockIdx.y;
  const ushort_t* A = half ? xca : xsa;
  const ushort_t* W = half ? w2b : w1b;
  const float* bias = half ? b2 : b1;
  const int t = threadIdx.x;
  const int oc = t & 7;
  const int rr = t >> 3;
  const int lane = t & 63, wave = t >> 6;
  const int m16 = lane & 15, quad = lane >> 4;
  const int wm = (wave >> 1) << 6, wn = (wave & 1) << 6;
  floatx4 acc[4][4];
#pragma unroll
  for (int i = 0; i < 4; ++i)
#pragma unroll
    for (int j = 0; j < 4; ++j) acc[i][j] = (floatx4)(0.f);
#pragma unroll 1
  for (int k0 = 0; k0 < 256; k0 += 64) {
    short8 a8[4], b8[4];
#pragma unroll
    for (int j = 0; j < 4; ++j) {
      const int r = rr + 32 * j;
      a8[j] = *(const short8*)&A[(size_t)(bm + r) * 256 + k0 + 8 * oc];
      b8[j] = *(const short8*)&W[(size_t)r * 256 + k0 + 8 * oc];
    }
    __syncthreads();
#pragma unroll
    for (int j = 0; j < 4; ++j) {
      const int r = rr + 32 * j;
      *(short8*)&As[r * 72 + 8 * oc] = a8[j];
      *(short8*)&Bs[r * 72 + 8 * oc] = b8[j];
    }
    __syncthreads();
#pragma unroll
    for (int ks = 0; ks < 2; ++ks) {
      short8 af[4], bf[4];
#pragma unroll
      for (int i = 0; i < 4; ++i)
        af[i] = *(const short8*)&As[(wm + i * 16 + m16) * 72 + ks * 32 + quad * 8];
#pragma unroll
      for (int j = 0; j < 4; ++j)
        bf[j] = *(const short8*)&Bs[(wn + j * 16 + m16) * 72 + ks * 32 + quad * 8];
#pragma unroll
      for (int i = 0; i < 4; ++i)
#pragma unroll
        for (int j = 0; j < 4; ++j)
          acc[i][j] = __builtin_amdgcn_mfma_f32_16x16x32_bf16(af[i], bf[j], acc[i][j], 0, 0, 0);
    }
  }
  const float slope = pa[0];
  float bj[4];
#pragma unroll
  for (int j = 0; j < 4; ++j) bj[j] = bias[wn + j * 16 + m16];
#pragma unroll
  for (int i = 0; i < 4; ++i)
#pragma unroll
    for (int r = 0; r < 4; ++r) {
      const int gr = bm + wm + i * 16 + quad * 4 + r;
#pragma unroll
      for (int j = 0; j < 4; ++j) {
        float v = acc[i][j][r] + bj[j];
        v = v >= 0.f ? v : slope * v;
        out[(size_t)gr * C_ + half * 128 + wn + j * 16 + m16] = v;
      }
    }
}

// ---------------------------------------------------------------------------
extern "C" void kernel_launch(void* const* d_in, const int* in_sizes, int n_in,
                              void* d_out, int out_size, void* d_ws, size_t ws_size,
                              hipStream_t stream) {
  (void)in_sizes; (void)n_in; (void)out_size; (void)ws_size;
  const float* x  = (const float*)d_in[0];
  // d_in[1] = bank (unused by forward)
  const float* Wq = (const float*)d_in[2];
  const float* WE = (const float*)d_in[3];
  const float* bE = (const float*)d_in[4];
  const float* t1 = (const float*)d_in[5];
  const float* t2 = (const float*)d_in[6];
  const float* W1 = (const float*)d_in[7];
  const float* b1 = (const float*)d_in[8];
  const float* W2 = (const float*)d_in[9];
  const float* b2 = (const float*)d_in[10];
  const float* pa = (const float*)d_in[11];
  float* out = (float*)d_out;

  float* ws = (float*)d_ws;
  size_t off = 0;
  float* Sqk = ws + off; off += (size_t)32 * 4096;              //   131,072
  float* rn  = ws + off; off += (size_t)B_ * 512;               //     4,096
  float* Gx  = ws + off; off += (size_t)B_ * GX_ROWS * 256;     //   655,360
  ushort_t* qv  = (ushort_t*)(ws + off); off += (size_t)M_ * 512 / 2;
  ushort_t* xsa = (ushort_t*)(ws + off); off += (size_t)M_ * C_ / 2;
  ushort_t* xca = (ushort_t*)(ws + off); off += (size_t)M_ * C_ / 2;
  ushort_t* ksb = (ushort_t*)(ws + off); off += 32 * 4096 / 2;  // bf16 [bh][p][d]
  ushort_t* vsb = (ushort_t*)(ws + off); off += 32 * 4096 / 2;  // bf16 [bh][d][p]
  ushort_t* ab  = (ushort_t*)(ws + off); off += 32 * 4096 / 2;  // bf16 attn
  ushort_t* xb  = (ushort_t*)(ws + off); off += (size_t)M_ * C_ / 2;   // bf16 x
  ushort_t* wqb = (ushort_t*)(ws + off); off += (size_t)OC_ * C_ / 2;  // bf16 Wq
  ushort_t* w1b = (ushort_t*)(ws + off); off += (size_t)128 * C_ / 2;
  ushort_t* w2b = (ushort_t*)(ws + off); off += (size_t)128 * C_ / 2;
  ushort_t* web = (ushort_t*)(ws + off); off += (size_t)P_ * N_ / 2;   // bf16 WE
  ushort_t* Gxb = (ushort_t*)(ws + off); off += (size_t)B_ * GX_ROWS * 256 / 2;
  ushort_t* T2b = (ushort_t*)(ws + off); off += (size_t)B_ * 512 * 256 / 2;

  hipMemsetAsync(Gx, 0, (size_t)B_ * GX_ROWS * 256 * sizeof(float), stream);

  k_cast<<<2048, 256, 0, stream>>>(x, Wq, W1, W2, WE, xb, wqb, w1b, w2b, web);
  k_gram<<<dim3(6, B_ * KSPLIT_G), 256, 0, stream>>>(xb, web, Gx);
  k_qv_mfma<<<dim3(M_ / 128, 4), 256, 0, stream>>>(xb, wqb, qv);
  k_gcast<<<640, 256, 0, stream>>>(Gx, Gxb);
  k_t2gemm<<<dim3(4, B_ * 2), 256, 0, stream>>>(wqb, Gxb, T2b);
  k_rn<<<1024, 256, 0, stream>>>(wqb, T2b, rn);
  k_small<<<dim3(32, 3), 64, 0, stream>>>(wqb, T2b, Gxb, bE, rn, t2, Sqk, ksb, vsb);
  k_ca_softmax<<<512, 256, 0, stream>>>(Sqk, rn, t1, ab);
  k_ca_mfma<<<dim3(32, 32), 256, 0, stream>>>(qv, ab, xca);
  k_sa_mfma<<<dim3(32, 64), 256, 0, stream>>>(qv, ksb, vsb, xsa);
  k_out_mfma<<<dim3(M_ / 128, 2), 256, 0, stream>>>(xsa, xca, w1b, b1, w2b, b2, pa, out);
}